// Round 3
// baseline (189.187 us; speedup 1.0000x reference)
//
#include <hip/hip_runtime.h>
#include <hip/hip_bf16.h>

#define CIN  64
#define HH   128
#define WW   128
#define COUT 128
#define HO   126
#define WO   126
#define NB   32
#define HW   (HH * WW)

typedef __bf16 bf16x8 __attribute__((ext_vector_type(8)));
typedef float f32x4  __attribute__((ext_vector_type(4)));
typedef float f32x16 __attribute__((ext_vector_type(16)));

// reorder weight [128][64][3][3] f32 -> ws [9][128][64] bf16
__global__ void wreorder_3556(const float* __restrict__ w, unsigned short* __restrict__ ws) {
    int idx = blockIdx.x * 256 + threadIdx.x;
    if (idx >= 9 * 128 * 64) return;
    int s = idx >> 13;
    int r = idx & 8191;
    int cout = r >> 6, ci = r & 63;
    __bf16 h = (__bf16)w[cout * 576 + ci * 9 + s];
    ws[idx] = __builtin_bit_cast(unsigned short, h);
}

// LDS: xs[row(3)][col(130)][ci(64)] bf16, granule XOR-swizzled by col&7; + pmin[4][128]
#define XS_BYTES   (3 * 130 * 128)            // 49920
#define SMEM_BYTES (XS_BYTES + 4 * 128 * 4)   // 51968

template<bool USE_WS>
__global__ __launch_bounds__(512, 2)
void conv_min_tanh_3556(const float* __restrict__ x, const float* __restrict__ w,
                        const float* __restrict__ bias,
                        const unsigned short* __restrict__ wsr,
                        float* __restrict__ out) {
    __shared__ __align__(16) unsigned char smem[SMEM_BYTES];
    unsigned char* xs = smem;
    float* pmin = (float*)(smem + XS_BYTES);

    // XCD-chunked bijective swizzle (4032 % 8 == 0)
    const int bid = blockIdx.x;
    const int blk = (bid & 7) * (NB * HO / 8) + (bid >> 3);
    const int b  = blk / HO;
    const int ho = blk - b * HO;

    const int tid  = threadIdx.x;
    const int lane = tid & 63;
    const int wid  = tid >> 6;
    const int waveM = wid >> 1;      // 0..3 -> cout base 32*waveM
    const int waveN = wid & 1;       // 0..1 -> col base 64*waveN
    const int l31 = lane & 31;
    const int l5  = lane >> 5;
    const int mbase = waveM * 32;
    const int cb    = waveN * 64;

    // ---- stage x tile: 768 col4-groups (4 cols x 8 ci each), f32x4 global loads
    {
        const float* xb = x + (size_t)b * (CIN * HW);
        #pragma unroll
        for (int it = 0; it < 2; ++it) {
            int g = it * 512 + tid;
            if (g < 768) {
                int col4 = g & 31;
                int cig  = (g >> 5) & 7;
                int row  = g >> 8;
                const float* src = xb + (size_t)(cig * 8) * HW + (size_t)(ho + row) * WW + col4 * 4;
                f32x4 v[8];
                #pragma unroll
                for (int j = 0; j < 8; ++j) v[j] = *(const f32x4*)(src + (size_t)j * HW);
                #pragma unroll
                for (int c = 0; c < 4; ++c) {
                    bf16x8 gr;
                    #pragma unroll
                    for (int j = 0; j < 8; ++j) gr[j] = (__bf16)v[j][c];
                    int col = col4 * 4 + c;
                    int addr = (row * 130 + col) * 128 + ((cig ^ (col & 7)) << 4);
                    *(bf16x8*)(xs + addr) = gr;
                }
            }
        }
        // zero pad cols 128,129 (read by kw-shifted fragments of discarded outputs)
        if (tid < 48) {
            int row = tid >> 4, col = 128 + ((tid >> 3) & 1), cig = tid & 7;
            bf16x8 z = {};
            int addr = (row * 130 + col) * 128 + ((cig ^ (col & 7)) << 4);
            *(bf16x8*)(xs + addr) = z;
        }
    }

    // ---- all weights for this wave's 32 couts -> 144 VGPRs (af[9][4])
    bf16x8 af[9][4];
    if (USE_WS) {
        const unsigned short* wbase = wsr + (size_t)(mbase + l31) * 64 + l5 * 8;
        #pragma unroll
        for (int s = 0; s < 9; ++s)
            #pragma unroll
            for (int t = 0; t < 4; ++t)
                af[s][t] = *(const bf16x8*)(wbase + s * 8192 + t * 16);
    } else {
        #pragma unroll
        for (int s = 0; s < 9; ++s)
            #pragma unroll
            for (int t = 0; t < 4; ++t)
                #pragma unroll
                for (int j = 0; j < 8; ++j)
                    af[s][t][j] = (__bf16)w[(mbase + l31) * 576 + (t * 16 + l5 * 8 + j) * 9 + s];
    }

    __syncthreads();   // xs ready; implicit vmcnt(0) also drains weight loads

    // ---- precomputed swizzled B base addresses: PA[n][kw]
    // addr(n,kw,t,kh) = kh*16640 + (PA[n][kw] ^ (t<<5))   [bits disjoint: col*128 >= bit7]
    int PA[2][3];
    #pragma unroll
    for (int n = 0; n < 2; ++n)
        #pragma unroll
        for (int kw = 0; kw < 3; ++kw) {
            int col = cb + n * 32 + l31 + kw;
            PA[n][kw] = col * 128 + ((l5 ^ (col & 7)) << 4);
        }

    f32x16 acc[2] = {};

    // ---- barrier-free K-loop: 9 slices x 4 ksteps x 2 ntiles
    #pragma unroll
    for (int s = 0; s < 9; ++s) {
        const int kh = s / 3, kw = s - kh * 3;     // compile-time
        const int khoff = kh * 16640;
        #pragma unroll
        for (int t = 0; t < 4; ++t) {
            bf16x8 b0 = *(const bf16x8*)(xs + khoff + (PA[0][kw] ^ (t << 5)));
            bf16x8 b1 = *(const bf16x8*)(xs + khoff + (PA[1][kw] ^ (t << 5)));
            acc[0] = __builtin_amdgcn_mfma_f32_32x32x16_bf16(af[s][t], b0, acc[0], 0, 0, 0);
            acc[1] = __builtin_amdgcn_mfma_f32_32x32x16_bf16(af[s][t], b1, acc[1], 0, 0, 0);
        }
    }

    // ---- epilogue: +bias, min over this wave's 32 couts, cross-lane, cross-wave
    float pm0 = 1e30f, pm1 = 1e30f;
    {
        const int rbase = mbase + 4 * l5;
        #pragma unroll
        for (int r = 0; r < 16; ++r) {
            float bv = bias[rbase + (r & 3) + 8 * (r >> 2)];
            pm0 = fminf(pm0, acc[0][r] + bv);
            pm1 = fminf(pm1, acc[1][r] + bv);
        }
    }
    pm0 = fminf(pm0, __shfl_xor(pm0, 32, 64));
    pm1 = fminf(pm1, __shfl_xor(pm1, 32, 64));
    if (l5 == 0) {
        pmin[waveM * 128 + cb + l31]      = pm0;
        pmin[waveM * 128 + cb + 32 + l31] = pm1;
    }
    __syncthreads();
    if (tid < WO) {
        float v = fminf(fminf(pmin[tid], pmin[128 + tid]),
                        fminf(pmin[256 + tid], pmin[384 + tid]));
        v = tanhf(tanhf(v));
        out[((size_t)b * HO + ho) * WO + tid] = v;
    }
}

extern "C" void kernel_launch(void* const* d_in, const int* in_sizes, int n_in,
                              void* d_out, int out_size, void* d_ws, size_t ws_size,
                              hipStream_t stream) {
    const float* x    = (const float*)d_in[0];
    const float* w    = (const float*)d_in[1];
    const float* bias = (const float*)d_in[2];
    float* out = (float*)d_out;

    const size_t ws_needed = (size_t)9 * 128 * 64 * 2;   // 147456 B
    if (ws_size >= ws_needed) {
        unsigned short* wsb = (unsigned short*)d_ws;
        wreorder_3556<<<288, 256, 0, stream>>>(w, wsb);
        conv_min_tanh_3556<true><<<NB * HO, 512, 0, stream>>>(x, w, bias, wsb, out);
    } else {
        conv_min_tanh_3556<false><<<NB * HO, 512, 0, stream>>>(x, w, bias, nullptr, out);
    }
}